// Round 15
// baseline (96.843 us; speedup 1.0000x reference)
//
#include <hip/hip_runtime.h>

// SAR quantizer: q, Q, Wn outputs.
// L=524288 rows, A=24 ADCs, B=8 bits, M=36 coefficient rows.
// VR = VREF = 1.8 / 2^3 = 0.225, noise scale = 0.01**0.5 = 0.1.
//
// R15: consolidated-window layout (DRAM stream locality test).
//   Old: each wave touched 6 regions ~MBs apart per iteration (q/Q/x at
//   i and i+T) -> ~50K concurrent streams chip-wide, DRAM page thrash.
//   New: block owns ONE contiguous 384-element window per iteration
//   (384 = 192 thr x 2 elem, mult of 24 -> per-thread fixed ADC column
//   kept: thread (q8,c) takes E+48*q8+c and E+48*q8+24+c). q AND Q both
//   staged in LDS block-wide, flushed dense (1KB/instr Q, 512B/instr q)
//   with nt. 3 streams per BLOCK now. 2 barriers/iter.
//   2560 blocks x 192 thr = 10 blocks/CU all resident (30 waves), no tail.
//   NWIN=32768 windows; block does 13 or 12 (block-uniform guards).

#define L_TOT   524288
#define A_ADC   24
#define M_ROWS  36
#define B_BITS  8
#define BLK     192
#define NBLK    2560
#define NXCD    8
#define N_TOT   (L_TOT * A_ADC)     // 12,582,912
#define WELEM   384                 // elements per window (mult of 24)
#define NWIN    (N_TOT / WELEM)     // 32768

typedef float f32x4 __attribute__((ext_vector_type(4)));
typedef float f32x2 __attribute__((ext_vector_type(2)));

// XOR swizzle on chunk index (involution within each aligned 64-group).
__device__ __forceinline__ int swz8(int c) { return c ^ ((c >> 3) & 7); }

__global__ __launch_bounds__(BLK) void sar_kernel(
    const float* __restrict__ x,
    const float* __restrict__ W,
    const float* __restrict__ nz,
    float* __restrict__ out_q,
    float* __restrict__ out_Q,
    float* __restrict__ out_Wn)
{
    // Bijective XCD swizzle (NBLK % 8 == 0): XCD k owns contiguous windows.
    const int bid = blockIdx.x;
    const int sb  = (bid & (NXCD - 1)) * (NBLK / NXCD) + (bid >> 3);

    const int tid = threadIdx.x;
    const int q8  = tid / 24;        // 0..7
    const int cc  = tid % 24;        // ADC column (fixed per thread)
    const int l0  = 48 * q8 + cc;    // element offset A within window
    const int l1  = l0 + 24;         // element offset B (same column)
    const int wl  = tid >> 6;        // wave in block (0..2)
    const int l   = tid & 63;        // lane

    __shared__ f32x4 sQ[WELEM * 2];  // 12KB, chunk-indexed (swz8)
    __shared__ float sq[WELEM];      // 1.5KB

    // Per-column coefficients: c[r] = (W[r][cc] + nz[r][cc]*0.1f) * 0.225f
    float c[M_ROWS];
#pragma unroll
    for (int r = 0; r < M_ROWS; ++r) {
        float wn = W[r * A_ADC + cc] + nz[r * A_ADC + cc] * 0.1f;
        c[r] = wn * 0.225f;
    }

    // Wn tail (864 floats): gid = sb*BLK+tid is bijective over [0, 491520).
    const int gid = sb * BLK + tid;
    if (gid < M_ROWS * A_ADC) {
        __builtin_nontemporal_store(W[gid] + nz[gid] * 0.1f, &out_Wn[gid]);
    }

    // SAR chain -> bitmask (bit j set => q_j = +1).
    // sign(x-bs+1e-30) == (x>=bs ? +1 : -1) exactly for these inputs;
    // bit?c:0.0f adds are bit-exact vs reference's t*c (t in {0,1}).
    auto sar = [&](float xv) -> unsigned {
        unsigned msk = 0u;
        int m = M_ROWS - 1;
#pragma unroll
        for (int jj = 0; jj < B_BITS; ++jj) {
            const int j = B_BITS - 1 - jj;
            float bs = c[m]; --m;
#pragma unroll
            for (int kk = j + 1; kk < B_BITS; ++kk) {
                bs += ((msk >> kk) & 1u) ? c[m] : 0.0f;
                --m;
            }
            if (xv >= bs) msk |= (1u << j);
        }
        return msk;
    };
    auto qsum = [](unsigned msk) -> float {
        float acc = 0.0f;
#pragma unroll
        for (int j = 0; j < B_BITS; ++j) {
            const float bwj = 0.225f * (float)(1 << j);
            acc += ((msk >> j) & 1u) ? bwj : 0.0f;
        }
        return acc;
    };

    // First window's x values.
    int win = sb;
    float xv0 = x[win * WELEM + l0];
    float xv1 = x[win * WELEM + l1];

    while (win < NWIN) {                    // block-uniform
        const int nwin = win + NBLK;
        float xn0 = 0.0f, xn1 = 0.0f;
        if (nwin < NWIN) {                  // block-uniform prefetch
            xn0 = x[nwin * WELEM + l0];
            xn1 = x[nwin * WELEM + l1];
        }

        const unsigned m0 = sar(xv0);
        const unsigned m1 = sar(xv1);

        // Stage q and Q into LDS (block-wide window).
        sq[l0] = qsum(m0);
        sq[l1] = qsum(m1);
        f32x4 v0, v1, v2, v3;
#pragma unroll
        for (int j = 0; j < 4; ++j) {
            v0[j] = ((m0 >> j) & 1u)       ? 1.0f : -1.0f;
            v1[j] = ((m0 >> (j + 4)) & 1u) ? 1.0f : -1.0f;
            v2[j] = ((m1 >> j) & 1u)       ? 1.0f : -1.0f;
            v3[j] = ((m1 >> (j + 4)) & 1u) ? 1.0f : -1.0f;
        }
        sQ[swz8(2 * l0)]     = v0;
        sQ[swz8(2 * l0 + 1)] = v1;
        sQ[swz8(2 * l1)]     = v2;
        sQ[swz8(2 * l1 + 1)] = v3;
        __syncthreads();

        // Flush q: 384 floats, thread -> floats 2*tid, 2*tid+1 (dense).
        {
            f32x2 qv; qv.x = sq[2 * tid]; qv.y = sq[2 * tid + 1];
            __builtin_nontemporal_store(
                qv, (f32x2*)(out_q + (long long)win * WELEM) + tid);
        }
        // Flush Q: 768 chunks; wave wl owns [wl*256, wl*256+256).
        f32x4* Qb = (f32x4*)out_Q + (long long)win * (WELEM * 2);
#pragma unroll
        for (int k = 0; k < 4; ++k) {
            const int ch = wl * 256 + k * 64 + l;
            __builtin_nontemporal_store(sQ[swz8(ch)], &Qb[ch]);
        }
        __syncthreads();   // protect LDS reuse next iteration

        xv0 = xn0;
        xv1 = xn1;
        win = nwin;
    }
}

extern "C" void kernel_launch(void* const* d_in, const int* in_sizes, int n_in,
                              void* d_out, int out_size, void* d_ws, size_t ws_size,
                              hipStream_t stream) {
    const float* x  = (const float*)d_in[0];
    const float* W  = (const float*)d_in[1];
    const float* nz = (const float*)d_in[2];
    float* out = (float*)d_out;

    float* out_q  = out;
    float* out_Q  = out + (long long)N_TOT;
    float* out_Wn = out + (long long)N_TOT * 9;

    // 2560 blocks x 192 threads = 10 blocks/CU, all resident, no tail.
    sar_kernel<<<NBLK, BLK, 0, stream>>>(x, W, nz, out_q, out_Q, out_Wn);
}

// Round 16
// 91.385 us; speedup vs baseline: 1.0597x; 1.0597x over previous
//
#include <hip/hip_runtime.h>

// SAR quantizer: q, Q, Wn outputs.
// L=524288 rows, A=24 ADCs, B=8 bits, M=36 coefficient rows.
// VR = VREF = 1.8 / 2^3 = 0.225, noise scale = 0.01**0.5 = 0.1.
//
// R16 = R12 geometry + FMA-form SAR (single change class: VALU reduction).
//   Bitmask form compiled to bfe+cndmask+add (3 VALU) per inner step;
//   float-bit form t_j in {0,1} uses ONE v_fmac_f32: bs = fma(t,c,bs).
//   Bit-exact: t*c is exact (0 or c), so fma's single rounding == the
//   reference's two-step round; t=0 adds +0.0f exactly as before.
//   qsum: acc = fma(t_j, bw_j, acc)  (t*bw exact -> identical).
//   Qgen: Q_j = fma(t_j, 2, -1) = exact +-1.
//   Single element/iter (unroll-2 proven neutral R9/R12) keeps VGPR ~55
//   (< 64 cliff). Theory: ~40us VALU (R4 probe) only partially overlaps
//   the ~74us memory floor; cutting VALU ~2.5x closes the ~20us gap.
//   Predict 83-88us if right; 91-95 => compute hidden, roofline next.

#define L_TOT   524288
#define A_ADC   24
#define M_ROWS  36
#define B_BITS  8
#define BLK     256
#define NBLK    3072
#define NXCD    8
#define N_TOT   (L_TOT * A_ADC)          // 12,582,912
#define T_STR   (NBLK * BLK)             // 786,432 (multiple of 24); N = 16*T

typedef float f32x4 __attribute__((ext_vector_type(4)));

// XOR bank-quad swizzle (involution, bijective on [0,128)).
__device__ __forceinline__ int swz(int c) { return c ^ ((c >> 3) & 7); }

__global__ __launch_bounds__(BLK) void sar_kernel(
    const float* __restrict__ x,
    const float* __restrict__ W,
    const float* __restrict__ nz,
    float* __restrict__ out_q,
    float* __restrict__ out_Q,
    float* __restrict__ out_Wn)
{
    // Bijective XCD swizzle (NBLK % 8 == 0).
    const int bid = blockIdx.x;
    const int sb  = (bid & (NXCD - 1)) * (NBLK / NXCD) + (bid >> 3);

    const int gid = sb * BLK + threadIdx.x;   // < T_STR; 32-bit safe
    const int a = gid % 24;          // ADC column of element gid (+ m*T_STR)
    const int w = threadIdx.x >> 6;  // wave id in block (0..3)
    const int l = threadIdx.x & 63;  // lane

    __shared__ f32x4 stage[BLK / 64][128]; // 2KB per wave (8KB/block)

    // Per-a coefficients: c[r] = (W[r][a] + noise[r][a]*0.1f) * 0.225f
    float c[M_ROWS];
#pragma unroll
    for (int r = 0; r < M_ROWS; ++r) {
        float wn = W[r * A_ADC + a] + nz[r * A_ADC + a] * 0.1f;
        c[r] = wn * 0.225f;
    }

    // Wn tail output (864 floats), once (gid is a bijection of thread id).
    if (gid < M_ROWS * A_ADC) {
        __builtin_nontemporal_store(W[gid] + nz[gid] * 0.1f, &out_Wn[gid]);
    }

    // Software pipeline, depth 2: xv = x[i], xn1 = x[i+T].
    float xv  = x[gid];              // gid < T < N
    float xn1 = x[gid + T_STR];      // gid + T < 2T < N

    // Exactly 16 iterations (N = 16 * T).
#pragma unroll 1
    for (int k = 0; k < 16; ++k) {
        const int i = gid + k * T_STR;

        // Prefetch x[i+2T] FIRST (oldest position in the VMEM queue, so
        // its wait never forces a drain of this iteration's stores).
        float xn2 = 0.0f;
        if (k < 14) xn2 = x[i + 2 * T_STR];   // uniform branch

        // SAR chain with float bits t_j in {0,1}: one fmac per inner step.
        // t_j = (x >= bs) — direct comparison (no x-bs subtraction; avoids
        // the -0/underflow pitfall). Bit-exact vs reference (see header).
        float t[B_BITS];
        int m = M_ROWS - 1;
#pragma unroll
        for (int jj = 0; jj < B_BITS; ++jj) {
            const int j = B_BITS - 1 - jj;
            float bs = c[m]; --m;            // Wn[m]*VREF
#pragma unroll
            for (int kk = j + 1; kk < B_BITS; ++kk) {
                bs = __builtin_fmaf(t[kk], c[m], bs);
                --m;
            }
            t[j] = (xv >= bs) ? 1.0f : 0.0f;
        }

        // q = sum_j t_j * (0.225 * 2^j), ascending j; fma bit-exact.
        float acc = 0.0f;
#pragma unroll
        for (int j = 0; j < B_BITS; ++j) {
            const float bwj = 0.225f * (float)(1 << j);
            acc = __builtin_fmaf(t[j], bwj, acc);
        }
        __builtin_nontemporal_store(acc, &out_q[i]);

        // --- Q output via LDS staging: Q_j = 2*t_j - 1 (exact +-1) ---
        f32x4 v0, v1;
#pragma unroll
        for (int j = 0; j < 4; ++j) {
            v0[j] = __builtin_fmaf(t[j],     2.0f, -1.0f);
            v1[j] = __builtin_fmaf(t[j + 4], 2.0f, -1.0f);
        }
        const int c0 = 2 * l, c1 = 2 * l + 1;
        stage[w][swz(c0)] = v0;
        stage[w][swz(c1)] = v1;
        // wave-private; compiler inserts lgkmcnt before the readback.
        f32x4* Qp = (f32x4*)out_Q + (long long)(i - l) * 2;
        const int r0 = l, r1 = 64 + l;
        __builtin_nontemporal_store(stage[w][swz(r0)], &Qp[r0]);
        __builtin_nontemporal_store(stage[w][swz(r1)], &Qp[r1]);

        xv  = xn1;
        xn1 = xn2;
    }
}

extern "C" void kernel_launch(void* const* d_in, const int* in_sizes, int n_in,
                              void* d_out, int out_size, void* d_ws, size_t ws_size,
                              hipStream_t stream) {
    const float* x  = (const float*)d_in[0];
    const float* W  = (const float*)d_in[1];
    const float* nz = (const float*)d_in[2];
    float* out = (float*)d_out;

    float* out_q  = out;
    float* out_Q  = out + (long long)N_TOT;
    float* out_Wn = out + (long long)N_TOT * 9;

    // 3072 blocks x 256 threads; stride T = 786432 (multiple of 24);
    // 16 single-element iterations per thread.
    sar_kernel<<<NBLK, BLK, 0, stream>>>(x, W, nz, out_q, out_Q, out_Wn);
}